// Round 4
// baseline (360.124 us; speedup 1.0000x reference)
//
#include <hip/hip_runtime.h>
#include <hip/hip_bf16.h>

#define D_MODEL 256
#define D_HID   128
#define SEQ     1024
#define NBATCH  32
#define NROWS   (NBATCH * SEQ)    // 32768
#define MASKV   -10000.0f
#define EPSLN   1e-5f

typedef unsigned short u16;
using bf16x8 = __attribute__((ext_vector_type(8))) short;   // 8 bf16 in 4 VGPRs
using f32x4  = __attribute__((ext_vector_type(4))) float;   // 4 fp32 acc

union U8 { uint4 v; u16 s[8]; };

__device__ __forceinline__ float bf2f(u16 u) {
    unsigned int x = ((unsigned int)u) << 16;
    return __uint_as_float(x);
}
__device__ __forceinline__ u16 f2bf(float f) {
    unsigned int u = __float_as_uint(f);
    u += 0x7fff + ((u >> 16) & 1);   // RNE
    return (u16)(u >> 16);
}

__device__ __forceinline__ void load8(const float* p, float* f) {
    float4 a = *(const float4*)p;
    float4 b = *(const float4*)(p + 4);
    f[0] = a.x; f[1] = a.y; f[2] = a.z; f[3] = a.w;
    f[4] = b.x; f[5] = b.y; f[6] = b.z; f[7] = b.w;
}
__device__ __forceinline__ void load8(const u16* p, float* f) {
    U8 u; u.v = *(const uint4*)p;
    #pragma unroll
    for (int e = 0; e < 8; e++) f[e] = bf2f(u.s[e]);
}
__device__ __forceinline__ void load4(const float* p, float* f) {
    float4 a = *(const float4*)p;
    f[0] = a.x; f[1] = a.y; f[2] = a.z; f[3] = a.w;
}
__device__ __forceinline__ void load4(const u16* p, float* f) {
    ushort4 v = *(const ushort4*)p;
    f[0] = bf2f(v.x); f[1] = bf2f(v.y); f[2] = bf2f(v.z); f[3] = bf2f(v.w);
}

// ---------------------------------------------------------------------------
// Weight transposes: fp32 W[K][N] -> bf16 WT[N][K]
// ---------------------------------------------------------------------------
__global__ __launch_bounds__(256) void transpose_weights(
    const float* __restrict__ wqkv, u16* __restrict__ wqkvT,
    const float* __restrict__ wproj, u16* __restrict__ wprojT,
    const float* __restrict__ wfc1, u16* __restrict__ wfc1T,
    const float* __restrict__ wfc2, u16* __restrict__ wfc2T) {
    int tid = blockIdx.x * 256 + threadIdx.x;
    int stride = gridDim.x * 256;
    for (int i = tid; i < 768 * 256; i += stride) {
        int n = i >> 8, k = i & 255;
        wqkvT[i] = f2bf(wqkv[k * 768 + n]);
    }
    for (int i = tid; i < 256 * 256; i += stride) {
        int n = i >> 8, k = i & 255;
        wprojT[i] = f2bf(wproj[k * 256 + n]);
    }
    for (int i = tid; i < 128 * 256; i += stride) {
        int n = i >> 8, k = i & 255;
        wfc1T[i] = f2bf(wfc1[k * 128 + n]);
    }
    for (int i = tid; i < 256 * 128; i += stride) {
        int n = i >> 7, k = i & 127;
        wfc2T[i] = f2bf(wfc2[k * 256 + n]);
    }
}

// ---------------------------------------------------------------------------
// LN stats: one wave per row -> (mu, rstd)
// ---------------------------------------------------------------------------
template <typename TX>
__global__ __launch_bounds__(256) void ln_stats(
    const TX* __restrict__ x, float2* __restrict__ st) {
    int wave = threadIdx.x >> 6, lane = threadIdx.x & 63;
    int row = blockIdx.x * 4 + wave;
    float f[4];
    load4(x + (size_t)row * D_MODEL + lane * 4, f);
    float s  = f[0] + f[1] + f[2] + f[3];
    float sq = f[0] * f[0] + f[1] * f[1] + f[2] * f[2] + f[3] * f[3];
    #pragma unroll
    for (int off = 1; off < 64; off <<= 1) {
        s  += __shfl_xor(s, off);
        sq += __shfl_xor(sq, off);
    }
    float mu   = s * (1.0f / 256.0f);
    float var  = sq * (1.0f / 256.0f) - mu * mu;
    float rstd = rsqrtf(var + EPSLN);
    if (lane == 0) st[row] = make_float2(mu, rstd);
}

// ---------------------------------------------------------------------------
// 128x64 GEMM tile mainloop. 4 waves in 2x2; each wave 64x32 (acc[4][2]).
// K staged in 128-chunks; LDS rows padded +8 (2-way bank aliasing = free).
// ---------------------------------------------------------------------------
#define GEMM_LDS_ELEMS ((128 + 64) * 136)

template <int K>
__device__ __forceinline__ void gemm_tile(
    const u16* __restrict__ A, const u16* __restrict__ BT,
    int m0, int n0, u16* lds, f32x4 acc[4][2]) {
    constexpr int KC = 128, KP = 136;
    u16* ldsA = lds;
    u16* ldsB = lds + 128 * KP;
    const int tid = threadIdx.x;
    const int lane = tid & 63, wave = tid >> 6;
    const int wr = (wave >> 1) * 64, wc = (wave & 1) * 32;
    const int row = lane & 15, quad = lane >> 4;

    for (int ks = 0; ks < K; ks += KC) {
        __syncthreads();
        for (int i = tid; i < 2048; i += 256) {          // A: 128 x 128
            int i8 = i * 8;
            int r = i8 >> 7, c = i8 & 127;
            *(uint4*)(ldsA + r * KP + c) =
                *(const uint4*)(A + (size_t)(m0 + r) * K + ks + c);
        }
        for (int i = tid; i < 1024; i += 256) {          // B: 64 x 128
            int i8 = i * 8;
            int r = i8 >> 7, c = i8 & 127;
            *(uint4*)(ldsB + r * KP + c) =
                *(const uint4*)(BT + (size_t)(n0 + r) * K + ks + c);
        }
        __syncthreads();
        #pragma unroll
        for (int k0 = 0; k0 < KC; k0 += 32) {
            bf16x8 a[4], b[2];
            #pragma unroll
            for (int mi = 0; mi < 4; mi++)
                a[mi] = *(const bf16x8*)(ldsA + (wr + mi * 16 + row) * KP + k0 + quad * 8);
            #pragma unroll
            for (int nj = 0; nj < 2; nj++)
                b[nj] = *(const bf16x8*)(ldsB + (wc + nj * 16 + row) * KP + k0 + quad * 8);
            #pragma unroll
            for (int mi = 0; mi < 4; mi++)
                #pragma unroll
                for (int nj = 0; nj < 2; nj++)
                    acc[mi][nj] = __builtin_amdgcn_mfma_f32_16x16x32_bf16(
                        a[mi], b[nj], acc[mi][nj], 0, 0, 0);
        }
    }
}

// LayerNorm fused into A-staging. TX = float (input x) or u16 (bf16 x2).
template <int K, typename TX>
__device__ __forceinline__ void gemm_tile_ln(
    const TX* __restrict__ X, const float2* __restrict__ st,
    const float* __restrict__ gamma, const float* __restrict__ beta,
    const u16* __restrict__ BT,
    int m0, int n0, u16* lds, f32x4 acc[4][2]) {
    constexpr int KC = 128, KP = 136;
    u16* ldsA = lds;
    u16* ldsB = lds + 128 * KP;
    const int tid = threadIdx.x;
    const int lane = tid & 63, wave = tid >> 6;
    const int wr = (wave >> 1) * 64, wc = (wave & 1) * 32;
    const int row = lane & 15, quad = lane >> 4;

    for (int ks = 0; ks < K; ks += KC) {
        __syncthreads();
        for (int i = tid; i < 2048; i += 256) {
            int i8 = i * 8;
            int r = i8 >> 7, c = i8 & 127;
            float2 s2 = st[m0 + r];
            float xf[8], gf[8], bf[8];
            load8(X + (size_t)(m0 + r) * K + ks + c, xf);
            load8(gamma + ks + c, gf);
            load8(beta + ks + c, bf);
            U8 o;
            #pragma unroll
            for (int e = 0; e < 8; e++)
                o.s[e] = f2bf((xf[e] - s2.x) * s2.y * gf[e] + bf[e]);
            *(uint4*)(ldsA + r * KP + c) = o.v;
        }
        for (int i = tid; i < 1024; i += 256) {
            int i8 = i * 8;
            int r = i8 >> 7, c = i8 & 127;
            *(uint4*)(ldsB + r * KP + c) =
                *(const uint4*)(BT + (size_t)(n0 + r) * K + ks + c);
        }
        __syncthreads();
        #pragma unroll
        for (int k0 = 0; k0 < KC; k0 += 32) {
            bf16x8 a[4], b[2];
            #pragma unroll
            for (int mi = 0; mi < 4; mi++)
                a[mi] = *(const bf16x8*)(ldsA + (wr + mi * 16 + row) * KP + k0 + quad * 8);
            #pragma unroll
            for (int nj = 0; nj < 2; nj++)
                b[nj] = *(const bf16x8*)(ldsB + (wc + nj * 16 + row) * KP + k0 + quad * 8);
            #pragma unroll
            for (int mi = 0; mi < 4; mi++)
                #pragma unroll
                for (int nj = 0; nj < 2; nj++)
                    acc[mi][nj] = __builtin_amdgcn_mfma_f32_16x16x32_bf16(
                        a[mi], b[nj], acc[mi][nj], 0, 0, 0);
        }
    }
}

#define ZERO_ACC(acc)                                        \
    _Pragma("unroll") for (int i_ = 0; i_ < 4; i_++)         \
    _Pragma("unroll") for (int j_ = 0; j_ < 2; j_++)         \
    _Pragma("unroll") for (int e_ = 0; e_ < 4; e_++) acc[i_][j_][e_] = 0.0f;

#define EPILOG_IDX                                           \
    int lane = threadIdx.x & 63, wave = threadIdx.x >> 6;    \
    int wr = (wave >> 1) * 64, wc = (wave & 1) * 32;         \
    int row = lane & 15, quad = lane >> 4;

// QKV + fused LN1 -> q (pre-scaled by 1/16), k, vT[b,256,s]
__global__ __launch_bounds__(256) void gemm_qkv(
    const float* __restrict__ x, const float2* __restrict__ st1,
    const float* __restrict__ g1, const float* __restrict__ be1,
    const u16* __restrict__ wqkvT, const float* __restrict__ b_qkv,
    u16* __restrict__ q, u16* __restrict__ kk, u16* __restrict__ vT) {
    __shared__ u16 lds[GEMM_LDS_ELEMS];
    f32x4 acc[4][2];
    ZERO_ACC(acc)
    int m0 = blockIdx.x * 128, n0 = blockIdx.y * 64;
    gemm_tile_ln<256, float>(x, st1, g1, be1, wqkvT, m0, n0, lds, acc);
    EPILOG_IDX
    #pragma unroll
    for (int mi = 0; mi < 4; mi++) {
        #pragma unroll
        for (int nj = 0; nj < 2; nj++) {
            int gn = n0 + wc + nj * 16 + row;
            float bias = b_qkv[gn];
            int gm = m0 + wr + mi * 16 + quad * 4;
            if (gn < 256) {          // q, pre-scaled by 1/sqrt(D)=1/16
                #pragma unroll
                for (int r = 0; r < 4; r++)
                    q[(size_t)(gm + r) * 256 + gn] =
                        f2bf((acc[mi][nj][r] + bias) * 0.0625f);
            } else if (gn < 512) {   // k
                int col = gn - 256;
                #pragma unroll
                for (int r = 0; r < 4; r++)
                    kk[(size_t)(gm + r) * 256 + col] = f2bf(acc[mi][nj][r] + bias);
            } else {                 // v -> vT[b][d][s]
                int d = gn - 512;
                int b = gm >> 10, s = gm & 1023;
                ushort4 pack;
                pack.x = f2bf(acc[mi][nj][0] + bias);
                pack.y = f2bf(acc[mi][nj][1] + bias);
                pack.z = f2bf(acc[mi][nj][2] + bias);
                pack.w = f2bf(acc[mi][nj][3] + bias);
                *(ushort4*)(vT + ((size_t)(b * 256 + d) << 10) + s) = pack;
            }
        }
    }
}

// proj: ao @ wproj + b + residual(x fp32) -> x2 (bf16)
__global__ __launch_bounds__(256) void gemm_proj(
    const u16* __restrict__ ao, const u16* __restrict__ wprojT,
    const float* __restrict__ b_proj, const float* __restrict__ x_in,
    u16* __restrict__ x2) {
    __shared__ u16 lds[GEMM_LDS_ELEMS];
    f32x4 acc[4][2];
    ZERO_ACC(acc)
    int m0 = blockIdx.x * 128, n0 = blockIdx.y * 64;
    gemm_tile<256>(ao, wprojT, m0, n0, lds, acc);
    EPILOG_IDX
    #pragma unroll
    for (int mi = 0; mi < 4; mi++)
        #pragma unroll
        for (int nj = 0; nj < 2; nj++) {
            int gn = n0 + wc + nj * 16 + row;
            float bias = b_proj[gn];
            int gm = m0 + wr + mi * 16 + quad * 4;
            #pragma unroll
            for (int r = 0; r < 4; r++) {
                size_t idx = (size_t)(gm + r) * 256 + gn;
                x2[idx] = f2bf(acc[mi][nj][r] + bias + x_in[idx]);
            }
        }
}

// fc1 + fused LN2 + ReLU -> a1 [32768,128]
__global__ __launch_bounds__(256) void gemm_fc1(
    const u16* __restrict__ x2, const float2* __restrict__ st2,
    const float* __restrict__ g2, const float* __restrict__ be2,
    const u16* __restrict__ wfc1T, const float* __restrict__ b_fc1,
    u16* __restrict__ a1) {
    __shared__ u16 lds[GEMM_LDS_ELEMS];
    f32x4 acc[4][2];
    ZERO_ACC(acc)
    int m0 = blockIdx.x * 128, n0 = blockIdx.y * 64;
    gemm_tile_ln<256, u16>(x2, st2, g2, be2, wfc1T, m0, n0, lds, acc);
    EPILOG_IDX
    #pragma unroll
    for (int mi = 0; mi < 4; mi++)
        #pragma unroll
        for (int nj = 0; nj < 2; nj++) {
            int gn = n0 + wc + nj * 16 + row;
            float bias = b_fc1[gn];
            int gm = m0 + wr + mi * 16 + quad * 4;
            #pragma unroll
            for (int r = 0; r < 4; r++) {
                float v = acc[mi][nj][r] + bias;
                a1[(size_t)(gm + r) * 128 + gn] = f2bf(fmaxf(v, 0.0f));
            }
        }
}

// fc2: a1 @ wfc2 + b + residual(x2) -> out (fp32)
__global__ __launch_bounds__(256) void gemm_fc2(
    const u16* __restrict__ a1, const u16* __restrict__ wfc2T,
    const float* __restrict__ b_fc2, const u16* __restrict__ x2,
    float* __restrict__ out) {
    __shared__ u16 lds[GEMM_LDS_ELEMS];
    f32x4 acc[4][2];
    ZERO_ACC(acc)
    int m0 = blockIdx.x * 128, n0 = blockIdx.y * 64;
    gemm_tile<128>(a1, wfc2T, m0, n0, lds, acc);
    EPILOG_IDX
    #pragma unroll
    for (int mi = 0; mi < 4; mi++)
        #pragma unroll
        for (int nj = 0; nj < 2; nj++) {
            int gn = n0 + wc + nj * 16 + row;
            float bias = b_fc2[gn];
            int gm = m0 + wr + mi * 16 + quad * 4;
            #pragma unroll
            for (int r = 0; r < 4; r++) {
                size_t idx = (size_t)(gm + r) * 256 + gn;
                out[idx] = acc[mi][nj][r] + bias + bf2f(x2[idx]);
            }
        }
}

// ---------------------------------------------------------------------------
// Flash-style causal attention v2.
//  - linear grid 512, swizzled so each CU gets one heavy + one light q-tile
//  - 64-wide K-tiles in LDS; V b-frags read straight from global vT (L2-hot)
//  - q pre-scaled by 1/16 in gemm_qkv; only diagonal tile applies the mask
//  - ao aliases q (block reads only its own 64 q-rows up front)
// ---------------------------------------------------------------------------
__global__ __launch_bounds__(256) void attn_kernel(
    const u16* __restrict__ q, const u16* __restrict__ k,
    const u16* __restrict__ vT, u16* __restrict__ ao) {
    constexpr int KP2 = 264;   // K-tile row pad (256+8)
    constexpr int PP  = 72;    // P row pad (64+8)
    __shared__ u16 k_lds[64 * KP2];     // 33792 B
    __shared__ u16 p_lds[4 * 16 * PP];  //  9216 B

    int j = blockIdx.x;
    int rr_ = j >> 5, b = j & 31;
    int qt = (rr_ < 8) ? (15 - rr_) : (rr_ - 8);   // heavy-first pairing
    int tid = threadIdx.x;
    int lane = tid & 63, wave = tid >> 6;
    int row = lane & 15, quad = lane >> 4;
    int q0 = qt * 64 + wave * 16;

    const u16* qb = q + ((size_t)b << 10) * 256;
    const u16* kb = k + ((size_t)b << 10) * 256;
    const u16* vb = vT + (((size_t)b * 256) << 10);

    bf16x8 qf[8];
    #pragma unroll
    for (int kf = 0; kf < 8; kf++)
        qf[kf] = *(const bf16x8*)(qb + (size_t)(q0 + row) * 256 + kf * 32 + quad * 8);

    f32x4 o[16];
    #pragma unroll
    for (int n = 0; n < 16; n++)
        #pragma unroll
        for (int e = 0; e < 4; e++) o[n][e] = 0.0f;
    float m_i[4], l_i[4];
    #pragma unroll
    for (int r = 0; r < 4; r++) { m_i[r] = -1e30f; l_i[r] = 0.0f; }

    int nkt = qt + 1;
    for (int kt = 0; kt < nkt; kt++) {
        int k0 = kt * 64;
        __syncthreads();
        for (int i = tid; i < 2048; i += 256) {   // K tile: 64 x 256
            int i8 = i * 8;
            int r = i8 >> 8, c = i8 & 255;
            *(uint4*)(k_lds + r * KP2 + c) =
                *(const uint4*)(kb + (size_t)(k0 + r) * 256 + c);
        }
        __syncthreads();

        // S = Q K^T : 16 x 64 per wave (4 n-frags)
        f32x4 s[4];
        #pragma unroll
        for (int jn = 0; jn < 4; jn++)
            #pragma unroll
            for (int e = 0; e < 4; e++) s[jn][e] = 0.0f;
        #pragma unroll
        for (int kf = 0; kf < 8; kf++) {
            #pragma unroll
            for (int jn = 0; jn < 4; jn++) {
                bf16x8 bfrag = *(const bf16x8*)(k_lds + (jn * 16 + row) * KP2
                                                + kf * 32 + quad * 8);
                s[jn] = __builtin_amdgcn_mfma_f32_16x16x32_bf16(qf[kf], bfrag, s[jn], 0, 0, 0);
            }
        }

        float sv[4][4];
        bool diag = (kt == qt);
        int qrow = q0 + quad * 4;
        #pragma unroll
        for (int jn = 0; jn < 4; jn++)
            #pragma unroll
            for (int r = 0; r < 4; r++) {
                float v = s[jn][r];
                if (diag && (k0 + jn * 16 + row > qrow + r)) v = MASKV;
                sv[jn][r] = v;
            }

        float al[4];
        #pragma unroll
        for (int r = 0; r < 4; r++) {
            float t = fmaxf(fmaxf(sv[0][r], sv[1][r]), fmaxf(sv[2][r], sv[3][r]));
            t = fmaxf(t, __shfl_xor(t, 1));
            t = fmaxf(t, __shfl_xor(t, 2));
            t = fmaxf(t, __shfl_xor(t, 4));
            t = fmaxf(t, __shfl_xor(t, 8));
            float mnew = fmaxf(m_i[r], t);
            al[r] = __expf(m_i[r] - mnew);
            float ps = 0.0f;
            #pragma unroll
            for (int jn = 0; jn < 4; jn++) {
                sv[jn][r] = __expf(sv[jn][r] - mnew);
                ps += sv[jn][r];
            }
            ps += __shfl_xor(ps, 1);
            ps += __shfl_xor(ps, 2);
            ps += __shfl_xor(ps, 4);
            ps += __shfl_xor(ps, 8);
            l_i[r] = l_i[r] * al[r] + ps;
            m_i[r] = mnew;
        }
        #pragma unroll
        for (int n = 0; n < 16; n++)
            #pragma unroll
            for (int r = 0; r < 4; r++) o[n][r] *= al[r];

        // P: C-layout -> LDS (wave-private) -> A-layout
        u16* pw = p_lds + wave * 16 * PP;
        #pragma unroll
        for (int jn = 0; jn < 4; jn++)
            #pragma unroll
            for (int r = 0; r < 4; r++)
                pw[(quad * 4 + r) * PP + jn * 16 + row] = f2bf(sv[jn][r]);
        bf16x8 pf0 = *(const bf16x8*)(pw + row * PP + quad * 8);
        bf16x8 pf1 = *(const bf16x8*)(pw + row * PP + 32 + quad * 8);

        // O += P V ; V b-frags straight from global (L2-resident)
        #pragma unroll
        for (int n = 0; n < 16; n++) {
            const u16* vrow = vb + ((size_t)(n * 16 + row) << 10) + k0 + quad * 8;
            bf16x8 bv0 = *(const bf16x8*)vrow;
            bf16x8 bv1 = *(const bf16x8*)(vrow + 32);
            o[n] = __builtin_amdgcn_mfma_f32_16x16x32_bf16(pf0, bv0, o[n], 0, 0, 0);
            o[n] = __builtin_amdgcn_mfma_f32_16x16x32_bf16(pf1, bv1, o[n], 0, 0, 0);
        }
    }

    u16* aob = ao + (((size_t)b << 10) + q0) * 256;
    #pragma unroll
    for (int r = 0; r < 4; r++) {
        float inv = 1.0f / l_i[r];
        #pragma unroll
        for (int n = 0; n < 16; n++)
            aob[(size_t)(quad * 4 + r) * 256 + n * 16 + row] = f2bf(o[n][r] * inv);
    }
}

// ---------------------------------------------------------------------------
extern "C" void kernel_launch(void* const* d_in, const int* in_sizes, int n_in,
                              void* d_out, int out_size, void* d_ws, size_t ws_size,
                              hipStream_t stream) {
    const float* x      = (const float*)d_in[0];
    const float* ln1_s  = (const float*)d_in[1];
    const float* ln1_b  = (const float*)d_in[2];
    const float* w_qkv  = (const float*)d_in[3];
    const float* b_qkv  = (const float*)d_in[4];
    const float* w_proj = (const float*)d_in[5];
    const float* b_proj = (const float*)d_in[6];
    const float* ln2_s  = (const float*)d_in[7];
    const float* ln2_b  = (const float*)d_in[8];
    const float* w_fc1  = (const float*)d_in[9];
    const float* b_fc1  = (const float*)d_in[10];
    const float* w_fc2  = (const float*)d_in[11];
    const float* b_fc2  = (const float*)d_in[12];
    float* out = (float*)d_out;

    u16* W = (u16*)d_ws;
    u16* wqkvT  = W;                           // 768*256
    u16* wprojT = wqkvT + 196608;              // 256*256
    u16* wfc1T  = wprojT + 65536;              // 128*256
    u16* wfc2T  = wfc1T + 32768;               // 256*128
    float2* st1 = (float2*)(wfc2T + 32768);    // 32768 float2
    float2* st2 = st1 + NROWS;
    u16* buf1   = (u16*)(st2 + NROWS);         // q, then attn-out (in place)
    u16* buf2   = buf1 + (size_t)NROWS * 256;  // k, then x2
    u16* buf3   = buf2 + (size_t)NROWS * 256;  // vT, then a1

    transpose_weights<<<dim3(64), dim3(256), 0, stream>>>(
        w_qkv, wqkvT, w_proj, wprojT, w_fc1, wfc1T, w_fc2, wfc2T);
    ln_stats<float><<<dim3(NROWS / 4), dim3(256), 0, stream>>>(x, st1);
    gemm_qkv<<<dim3(NROWS / 128, 12), dim3(256), 0, stream>>>(
        x, st1, ln1_s, ln1_b, wqkvT, b_qkv, buf1, buf2, buf3);
    attn_kernel<<<dim3(512), dim3(256), 0, stream>>>(
        buf1, buf2, buf3, buf1);
    gemm_proj<<<dim3(NROWS / 128, 4), dim3(256), 0, stream>>>(
        buf1, wprojT, b_proj, x, buf2);
    ln_stats<u16><<<dim3(NROWS / 4), dim3(256), 0, stream>>>(buf2, st2);
    gemm_fc1<<<dim3(NROWS / 128, 2), dim3(256), 0, stream>>>(
        buf2, st2, ln2_s, ln2_b, wfc1T, b_fc1, buf3);
    gemm_fc2<<<dim3(NROWS / 128, 4), dim3(256), 0, stream>>>(
        buf3, wfc2T, b_fc2, buf2, out);
}

// Round 5
// 301.027 us; speedup vs baseline: 1.1963x; 1.1963x over previous
//
#include <hip/hip_runtime.h>
#include <hip/hip_bf16.h>

#define D_MODEL 256
#define D_HID   128
#define SEQ     1024
#define NBATCH  32
#define NROWS   (NBATCH * SEQ)    // 32768
#define MASKV   -10000.0f
#define EPSLN   1e-5f

typedef unsigned short u16;
using bf16x8 = __attribute__((ext_vector_type(8))) short;
using f32x4  = __attribute__((ext_vector_type(4))) float;

union U8 { uint4 v; u16 s[8]; };

__device__ __forceinline__ float bf2f(u16 u) {
    unsigned int x = ((unsigned int)u) << 16;
    return __uint_as_float(x);
}
__device__ __forceinline__ u16 f2bf(float f) {
    unsigned int u = __float_as_uint(f);
    u += 0x7fff + ((u >> 16) & 1);   // RNE
    return (u16)(u >> 16);
}
__device__ __forceinline__ void load4(const float* p, float* f) {
    float4 a = *(const float4*)p;
    f[0] = a.x; f[1] = a.y; f[2] = a.z; f[3] = a.w;
}
__device__ __forceinline__ void load4(const u16* p, float* f) {
    ushort4 v = *(const ushort4*)p;
    f[0] = bf2f(v.x); f[1] = bf2f(v.y); f[2] = bf2f(v.z); f[3] = bf2f(v.w);
}

// ---------------------------------------------------------------------------
// Weight transposes: fp32 W[K][N] -> bf16 WT[N][K]
// ---------------------------------------------------------------------------
__global__ __launch_bounds__(256) void transpose_weights(
    const float* __restrict__ wqkv, u16* __restrict__ wqkvT,
    const float* __restrict__ wproj, u16* __restrict__ wprojT,
    const float* __restrict__ wfc1, u16* __restrict__ wfc1T,
    const float* __restrict__ wfc2, u16* __restrict__ wfc2T) {
    int tid = blockIdx.x * 256 + threadIdx.x;
    int stride = gridDim.x * 256;
    for (int i = tid; i < 768 * 256; i += stride) {
        int n = i >> 8, k = i & 255;
        wqkvT[i] = f2bf(wqkv[k * 768 + n]);
    }
    for (int i = tid; i < 256 * 256; i += stride) {
        int n = i >> 8, k = i & 255;
        wprojT[i] = f2bf(wproj[k * 256 + n]);
    }
    for (int i = tid; i < 128 * 256; i += stride) {
        int n = i >> 8, k = i & 255;
        wfc1T[i] = f2bf(wfc1[k * 128 + n]);
    }
    for (int i = tid; i < 256 * 128; i += stride) {
        int n = i >> 7, k = i & 127;
        wfc2T[i] = f2bf(wfc2[k * 256 + n]);
    }
}

// ---------------------------------------------------------------------------
// Fused LayerNorm: one wave per row (256 cols, 4/lane), writes bf16 row.
// ---------------------------------------------------------------------------
template <typename TX>
__global__ __launch_bounds__(256) void ln_fused(
    const TX* __restrict__ x, const float* __restrict__ gamma,
    const float* __restrict__ beta, u16* __restrict__ out) {
    int wave = threadIdx.x >> 6, lane = threadIdx.x & 63;
    int row = blockIdx.x * 4 + wave;
    float f[4];
    load4(x + (size_t)row * D_MODEL + lane * 4, f);
    float s  = f[0] + f[1] + f[2] + f[3];
    float sq = f[0] * f[0] + f[1] * f[1] + f[2] * f[2] + f[3] * f[3];
    #pragma unroll
    for (int off = 1; off < 64; off <<= 1) {
        s  += __shfl_xor(s, off);
        sq += __shfl_xor(sq, off);
    }
    float mu   = s * (1.0f / 256.0f);
    float var  = sq * (1.0f / 256.0f) - mu * mu;
    float rstd = rsqrtf(var + EPSLN);
    float g[4], be[4];
    load4(gamma + lane * 4, g);
    load4(beta + lane * 4, be);
    ushort4 o;
    o.x = f2bf((f[0] - mu) * rstd * g[0] + be[0]);
    o.y = f2bf((f[1] - mu) * rstd * g[1] + be[1]);
    o.z = f2bf((f[2] - mu) * rstd * g[2] + be[2]);
    o.w = f2bf((f[3] - mu) * rstd * g[3] + be[3]);
    *(ushort4*)(out + (size_t)row * D_MODEL + lane * 4) = o;
}

// ---------------------------------------------------------------------------
// 128x64 GEMM tile mainloop. 4 waves in 2x2; each wave 64x32 (acc[4][2]).
// ---------------------------------------------------------------------------
#define GEMM_LDS_ELEMS ((128 + 64) * 136)

template <int K>
__device__ __forceinline__ void gemm_tile(
    const u16* __restrict__ A, const u16* __restrict__ BT,
    int m0, int n0, u16* lds, f32x4 acc[4][2]) {
    constexpr int KC = 128, KP = 136;
    u16* ldsA = lds;
    u16* ldsB = lds + 128 * KP;
    const int tid = threadIdx.x;
    const int lane = tid & 63, wave = tid >> 6;
    const int wr = (wave >> 1) * 64, wc = (wave & 1) * 32;
    const int row = lane & 15, quad = lane >> 4;

    for (int ks = 0; ks < K; ks += KC) {
        __syncthreads();
        for (int i = tid; i < 2048; i += 256) {          // A: 128 x 128
            int i8 = i * 8;
            int r = i8 >> 7, c = i8 & 127;
            *(uint4*)(ldsA + r * KP + c) =
                *(const uint4*)(A + (size_t)(m0 + r) * K + ks + c);
        }
        for (int i = tid; i < 1024; i += 256) {          // B: 64 x 128
            int i8 = i * 8;
            int r = i8 >> 7, c = i8 & 127;
            *(uint4*)(ldsB + r * KP + c) =
                *(const uint4*)(BT + (size_t)(n0 + r) * K + ks + c);
        }
        __syncthreads();
        #pragma unroll
        for (int k0 = 0; k0 < KC; k0 += 32) {
            bf16x8 a[4], b[2];
            #pragma unroll
            for (int mi = 0; mi < 4; mi++)
                a[mi] = *(const bf16x8*)(ldsA + (wr + mi * 16 + row) * KP + k0 + quad * 8);
            #pragma unroll
            for (int nj = 0; nj < 2; nj++)
                b[nj] = *(const bf16x8*)(ldsB + (wc + nj * 16 + row) * KP + k0 + quad * 8);
            #pragma unroll
            for (int mi = 0; mi < 4; mi++)
                #pragma unroll
                for (int nj = 0; nj < 2; nj++)
                    acc[mi][nj] = __builtin_amdgcn_mfma_f32_16x16x32_bf16(
                        a[mi], b[nj], acc[mi][nj], 0, 0, 0);
        }
    }
}

#define ZERO_ACC(acc)                                        \
    _Pragma("unroll") for (int i_ = 0; i_ < 4; i_++)         \
    _Pragma("unroll") for (int j_ = 0; j_ < 2; j_++)         \
    _Pragma("unroll") for (int e_ = 0; e_ < 4; e_++) acc[i_][j_][e_] = 0.0f;

#define EPILOG_IDX                                           \
    int lane = threadIdx.x & 63, wave = threadIdx.x >> 6;    \
    int wr = (wave >> 1) * 64, wc = (wave & 1) * 32;         \
    int row = lane & 15, quad = lane >> 4;

// QKV: h @ wqkv + b -> q (pre-scaled 1/16), k, vT[b,256,s]
__global__ __launch_bounds__(256) void gemm_qkv(
    const u16* __restrict__ h, const u16* __restrict__ wqkvT,
    const float* __restrict__ b_qkv,
    u16* __restrict__ q, u16* __restrict__ kk, u16* __restrict__ vT) {
    __shared__ u16 lds[GEMM_LDS_ELEMS];
    f32x4 acc[4][2];
    ZERO_ACC(acc)
    int m0 = blockIdx.x * 128, n0 = blockIdx.y * 64;
    gemm_tile<256>(h, wqkvT, m0, n0, lds, acc);
    EPILOG_IDX
    #pragma unroll
    for (int mi = 0; mi < 4; mi++) {
        #pragma unroll
        for (int nj = 0; nj < 2; nj++) {
            int gn = n0 + wc + nj * 16 + row;
            float bias = b_qkv[gn];
            int gm = m0 + wr + mi * 16 + quad * 4;
            if (gn < 256) {          // q, pre-scaled by 1/sqrt(D)=1/16
                #pragma unroll
                for (int r = 0; r < 4; r++)
                    q[(size_t)(gm + r) * 256 + gn] =
                        f2bf((acc[mi][nj][r] + bias) * 0.0625f);
            } else if (gn < 512) {   // k
                int col = gn - 256;
                #pragma unroll
                for (int r = 0; r < 4; r++)
                    kk[(size_t)(gm + r) * 256 + col] = f2bf(acc[mi][nj][r] + bias);
            } else {                 // v -> vT[b][d][s]
                int d = gn - 512;
                int b = gm >> 10, s = gm & 1023;
                ushort4 pack;
                pack.x = f2bf(acc[mi][nj][0] + bias);
                pack.y = f2bf(acc[mi][nj][1] + bias);
                pack.z = f2bf(acc[mi][nj][2] + bias);
                pack.w = f2bf(acc[mi][nj][3] + bias);
                *(ushort4*)(vT + ((size_t)(b * 256 + d) << 10) + s) = pack;
            }
        }
    }
}

// proj: ao @ wproj + b + residual(x fp32) -> x2 (bf16)
__global__ __launch_bounds__(256) void gemm_proj(
    const u16* __restrict__ ao, const u16* __restrict__ wprojT,
    const float* __restrict__ b_proj, const float* __restrict__ x_in,
    u16* __restrict__ x2) {
    __shared__ u16 lds[GEMM_LDS_ELEMS];
    f32x4 acc[4][2];
    ZERO_ACC(acc)
    int m0 = blockIdx.x * 128, n0 = blockIdx.y * 64;
    gemm_tile<256>(ao, wprojT, m0, n0, lds, acc);
    EPILOG_IDX
    #pragma unroll
    for (int mi = 0; mi < 4; mi++)
        #pragma unroll
        for (int nj = 0; nj < 2; nj++) {
            int gn = n0 + wc + nj * 16 + row;
            float bias = b_proj[gn];
            int gm = m0 + wr + mi * 16 + quad * 4;
            #pragma unroll
            for (int r = 0; r < 4; r++) {
                size_t idx = (size_t)(gm + r) * 256 + gn;
                x2[idx] = f2bf(acc[mi][nj][r] + bias + x_in[idx]);
            }
        }
}

// fc1: h2 @ wfc1 + b, ReLU -> a1
__global__ __launch_bounds__(256) void gemm_fc1(
    const u16* __restrict__ h2, const u16* __restrict__ wfc1T,
    const float* __restrict__ b_fc1, u16* __restrict__ a1) {
    __shared__ u16 lds[GEMM_LDS_ELEMS];
    f32x4 acc[4][2];
    ZERO_ACC(acc)
    int m0 = blockIdx.x * 128, n0 = blockIdx.y * 64;
    gemm_tile<256>(h2, wfc1T, m0, n0, lds, acc);
    EPILOG_IDX
    #pragma unroll
    for (int mi = 0; mi < 4; mi++)
        #pragma unroll
        for (int nj = 0; nj < 2; nj++) {
            int gn = n0 + wc + nj * 16 + row;
            float bias = b_fc1[gn];
            int gm = m0 + wr + mi * 16 + quad * 4;
            #pragma unroll
            for (int r = 0; r < 4; r++) {
                float v = acc[mi][nj][r] + bias;
                a1[(size_t)(gm + r) * 128 + gn] = f2bf(fmaxf(v, 0.0f));
            }
        }
}

// fc2: a1 @ wfc2 + b + residual(x2) -> out (fp32)
__global__ __launch_bounds__(256) void gemm_fc2(
    const u16* __restrict__ a1, const u16* __restrict__ wfc2T,
    const float* __restrict__ b_fc2, const u16* __restrict__ x2,
    float* __restrict__ out) {
    __shared__ u16 lds[GEMM_LDS_ELEMS];
    f32x4 acc[4][2];
    ZERO_ACC(acc)
    int m0 = blockIdx.x * 128, n0 = blockIdx.y * 64;
    gemm_tile<128>(a1, wfc2T, m0, n0, lds, acc);
    EPILOG_IDX
    #pragma unroll
    for (int mi = 0; mi < 4; mi++)
        #pragma unroll
        for (int nj = 0; nj < 2; nj++) {
            int gn = n0 + wc + nj * 16 + row;
            float bias = b_fc2[gn];
            int gm = m0 + wr + mi * 16 + quad * 4;
            #pragma unroll
            for (int r = 0; r < 4; r++) {
                size_t idx = (size_t)(gm + r) * 256 + gn;
                out[idx] = acc[mi][nj][r] + bias + bf2f(x2[idx]);
            }
        }
}

// ---------------------------------------------------------------------------
// Flash attention v3: 32 q-rows/block, grid 1024 (32 qtiles x 32 batches).
// Waves 0/1: rows 0-15/16-31, even k-tiles; waves 2/3: same rows, odd k-tiles.
// 64-wide K+V super-tiles staged in LDS; split-K states merged via LDS.
// qt swizzle: per 4-block CU group, total work sums exactly to the mean.
// ---------------------------------------------------------------------------
__global__ __launch_bounds__(256) void attn_kernel(
    const u16* __restrict__ q, const u16* __restrict__ k,
    const u16* __restrict__ vT, u16* __restrict__ ao) {
    constexpr int KP2 = 264;   // K rows pad (256+8)
    constexpr int VP  = 72;    // V rows pad (64+8)
    constexpr int PP  = 40;    // P rows pad (32+8)
    __shared__ u16 k_lds[64 * KP2];     // 33792 B (reused as fp32 O-merge buf)
    __shared__ u16 v_lds[256 * VP];     // 36864 B
    __shared__ u16 p_lds[4 * 16 * PP];  //  5120 B
    __shared__ float merge_ml[2][16][2];

    int j = blockIdx.x;
    int b = j & 31, rr = j >> 5;           // rr 0..31
    int g = rr & 7, qd = rr >> 3;
    int qt;                                 // balanced swizzle
    switch (qd) {
        case 0:  qt = g;      break;
        case 1:  qt = 15 - g; break;
        case 2:  qt = 16 + g; break;
        default: qt = 31 - g; break;
    }
    int tid = threadIdx.x;
    int lane = tid & 63, wave = tid >> 6;
    int row = lane & 15, quad = lane >> 4;
    int qsub = wave & 1, kpar = wave >> 1;
    int q0 = qt * 32;
    int qrow0 = q0 + qsub * 16;

    const u16* qb = q + ((size_t)b << 10) * 256;
    const u16* kb = k + ((size_t)b << 10) * 256;
    const u16* vb = vT + (((size_t)b * 256) << 10);

    bf16x8 qf[8];
    #pragma unroll
    for (int kf = 0; kf < 8; kf++)
        qf[kf] = *(const bf16x8*)(qb + (size_t)(qrow0 + row) * 256 + kf * 32 + quad * 8);

    f32x4 o[16];
    #pragma unroll
    for (int n = 0; n < 16; n++)
        #pragma unroll
        for (int e = 0; e < 4; e++) o[n][e] = 0.0f;
    float m_i[4], l_i[4];
    #pragma unroll
    for (int r = 0; r < 4; r++) { m_i[r] = -1e30f; l_i[r] = 0.0f; }

    int nkt = qt + 1;                  // 32-wide k-tiles
    int nsuper = (nkt + 1) >> 1;       // 64-wide staged super-tiles
    for (int s = 0; s < nsuper; s++) {
        int k0 = s * 64;
        __syncthreads();
        for (int i = tid; i < 2048; i += 256) {     // K: 64 x 256
            int i8 = i * 8;
            int r = i8 >> 8, c = i8 & 255;
            *(uint4*)(k_lds + r * KP2 + c) =
                *(const uint4*)(kb + (size_t)(k0 + r) * 256 + c);
        }
        {   // V: row d=tid, 64 cols
            const u16* src = vb + ((size_t)tid << 10) + k0;
            u16* dst = v_lds + tid * VP;
            #pragma unroll
            for (int u = 0; u < 8; u++)
                *(uint4*)(dst + u * 8) = *(const uint4*)(src + u * 8);
        }
        __syncthreads();

        int kt = 2 * s + kpar;
        if (kt >= nkt) continue;
        int kk0 = kt * 32;               // global k base of this wave's half
        int loff = kpar * 32;            // LDS col offset

        // S = Q K^T : 16 x 32 (2 n-frags)
        f32x4 sf[2];
        #pragma unroll
        for (int jn = 0; jn < 2; jn++)
            #pragma unroll
            for (int e = 0; e < 4; e++) sf[jn][e] = 0.0f;
        #pragma unroll
        for (int kf = 0; kf < 8; kf++)
            #pragma unroll
            for (int jn = 0; jn < 2; jn++) {
                bf16x8 bfrag = *(const bf16x8*)(k_lds + (loff + jn * 16 + row) * KP2
                                                + kf * 32 + quad * 8);
                sf[jn] = __builtin_amdgcn_mfma_f32_16x16x32_bf16(qf[kf], bfrag, sf[jn], 0, 0, 0);
            }

        float sv[2][4];
        bool diag = (kt == qt);          // only the diagonal tile needs masking
        int qrow = qrow0 + quad * 4;
        #pragma unroll
        for (int jn = 0; jn < 2; jn++)
            #pragma unroll
            for (int r = 0; r < 4; r++) {
                float v = sf[jn][r];
                if (diag && (kk0 + jn * 16 + row > qrow + r)) v = MASKV;
                sv[jn][r] = v;
            }

        float al[4];
        #pragma unroll
        for (int r = 0; r < 4; r++) {
            float t = fmaxf(sv[0][r], sv[1][r]);
            t = fmaxf(t, __shfl_xor(t, 1));
            t = fmaxf(t, __shfl_xor(t, 2));
            t = fmaxf(t, __shfl_xor(t, 4));
            t = fmaxf(t, __shfl_xor(t, 8));
            float mnew = fmaxf(m_i[r], t);
            al[r] = __expf(m_i[r] - mnew);
            float ps = 0.0f;
            #pragma unroll
            for (int jn = 0; jn < 2; jn++) {
                sv[jn][r] = __expf(sv[jn][r] - mnew);
                ps += sv[jn][r];
            }
            ps += __shfl_xor(ps, 1);
            ps += __shfl_xor(ps, 2);
            ps += __shfl_xor(ps, 4);
            ps += __shfl_xor(ps, 8);
            l_i[r] = l_i[r] * al[r] + ps;
            m_i[r] = mnew;
        }
        #pragma unroll
        for (int n = 0; n < 16; n++)
            #pragma unroll
            for (int r = 0; r < 4; r++) o[n][r] *= al[r];

        // P: C-layout -> wave-private LDS -> A-layout (one frag, K=32)
        u16* pw = p_lds + wave * 16 * PP;
        #pragma unroll
        for (int jn = 0; jn < 2; jn++)
            #pragma unroll
            for (int r = 0; r < 4; r++)
                pw[(quad * 4 + r) * PP + jn * 16 + row] = f2bf(sv[jn][r]);
        bf16x8 pf = *(const bf16x8*)(pw + row * PP + quad * 8);

        // O += P V  (V from LDS, this wave's 32-col half)
        #pragma unroll
        for (int n = 0; n < 16; n++) {
            bf16x8 bv = *(const bf16x8*)(v_lds + (n * 16 + row) * VP + loff + quad * 8);
            o[n] = __builtin_amdgcn_mfma_f32_16x16x32_bf16(pf, bv, o[n], 0, 0, 0);
        }
    }

    // ---- split-K merge: waves 2/3 hand (m,l,O) to waves 0/1 via LDS ----
    __syncthreads();
    float* ob = (float*)k_lds;           // 2 x 16 x 256 fp32 = 32 KB
    if (kpar == 1) {
        if (row == 0) {
            #pragma unroll
            for (int r = 0; r < 4; r++) {
                merge_ml[qsub][quad * 4 + r][0] = m_i[r];
                merge_ml[qsub][quad * 4 + r][1] = l_i[r];
            }
        }
        float* obq = ob + qsub * 16 * 256;
        #pragma unroll
        for (int n = 0; n < 16; n++)
            #pragma unroll
            for (int r = 0; r < 4; r++)
                obq[(quad * 4 + r) * 256 + n * 16 + row] = o[n][r];
    }
    __syncthreads();
    if (kpar == 0) {
        float fB[4], inv[4];
        #pragma unroll
        for (int r = 0; r < 4; r++) {
            float mB = merge_ml[qsub][quad * 4 + r][0];
            float lB = merge_ml[qsub][quad * 4 + r][1];
            float ms = fmaxf(m_i[r], mB);
            float fA = __expf(m_i[r] - ms);
            fB[r] = __expf(mB - ms);
            float ls = l_i[r] * fA + lB * fB[r];
            inv[r] = fA / ls;            // fold fA into the normalizer
            fB[r] = fB[r] / ls;
        }
        const float* obq = ob + qsub * 16 * 256;
        u16* aob = ao + (((size_t)b << 10) + qrow0) * 256;
        #pragma unroll
        for (int r = 0; r < 4; r++)
            #pragma unroll
            for (int n = 0; n < 16; n++) {
                float val = o[n][r] * inv[r]
                          + obq[(quad * 4 + r) * 256 + n * 16 + row] * fB[r];
                aob[(size_t)(quad * 4 + r) * 256 + n * 16 + row] = f2bf(val);
            }
    }
}

// ---------------------------------------------------------------------------
extern "C" void kernel_launch(void* const* d_in, const int* in_sizes, int n_in,
                              void* d_out, int out_size, void* d_ws, size_t ws_size,
                              hipStream_t stream) {
    const float* x      = (const float*)d_in[0];
    const float* ln1_s  = (const float*)d_in[1];
    const float* ln1_b  = (const float*)d_in[2];
    const float* w_qkv  = (const float*)d_in[3];
    const float* b_qkv  = (const float*)d_in[4];
    const float* w_proj = (const float*)d_in[5];
    const float* b_proj = (const float*)d_in[6];
    const float* ln2_s  = (const float*)d_in[7];
    const float* ln2_b  = (const float*)d_in[8];
    const float* w_fc1  = (const float*)d_in[9];
    const float* b_fc1  = (const float*)d_in[10];
    const float* w_fc2  = (const float*)d_in[11];
    const float* b_fc2  = (const float*)d_in[12];
    float* out = (float*)d_out;

    // LN outputs live inside d_out (33.5 MB = 2 x 16.8 MB bf16), dead before
    // fc2 overwrites it. d_out is re-poisoned each launch; we write-then-read.
    u16* h  = (u16*)d_out;                     // LN1(x)
    u16* h2 = h + (size_t)NROWS * 256;         // LN2(x2)

    u16* W = (u16*)d_ws;
    u16* wqkvT  = W;                           // 768*256
    u16* wprojT = wqkvT + 196608;              // 256*256
    u16* wfc1T  = wprojT + 65536;              // 128*256
    u16* wfc2T  = wfc1T + 32768;               // 256*128
    u16* buf1   = wfc2T + 32768;               // q, then attn-out (in place)
    u16* buf2   = buf1 + (size_t)NROWS * 256;  // k, then x2
    u16* buf3   = buf2 + (size_t)NROWS * 256;  // vT, then a1

    transpose_weights<<<dim3(64), dim3(256), 0, stream>>>(
        w_qkv, wqkvT, w_proj, wprojT, w_fc1, wfc1T, w_fc2, wfc2T);
    ln_fused<float><<<dim3(NROWS / 4), dim3(256), 0, stream>>>(
        x, ln1_s, ln1_b, h);
    gemm_qkv<<<dim3(NROWS / 128, 12), dim3(256), 0, stream>>>(
        h, wqkvT, b_qkv, buf1, buf2, buf3);
    attn_kernel<<<dim3(1024), dim3(256), 0, stream>>>(
        buf1, buf2, buf3, buf1);
    gemm_proj<<<dim3(NROWS / 128, 4), dim3(256), 0, stream>>>(
        buf1, wprojT, b_proj, x, buf2);
    ln_fused<u16><<<dim3(NROWS / 4), dim3(256), 0, stream>>>(
        buf2, ln2_s, ln2_b, h2);
    gemm_fc1<<<dim3(NROWS / 128, 2), dim3(256), 0, stream>>>(
        h2, wfc1T, b_fc1, buf3);
    gemm_fc2<<<dim3(NROWS / 128, 4), dim3(256), 0, stream>>>(
        buf3, wfc2T, b_fc2, buf2, out);
}